// Round 10
// baseline (451.314 us; speedup 1.0000x reference)
//
#include <hip/hip_runtime.h>
#include <hip/hip_bf16.h>

typedef float  f32x4  __attribute__((ext_vector_type(4)));
typedef unsigned long long u64;

#define N_ROWS 65536
#define N_F    512
#define N_CLU  1024

template <bool HI>
static __device__ __forceinline__ unsigned pk8(float a, float b, unsigned old) {
  return (unsigned)__builtin_amdgcn_cvt_pk_fp8_f32(a, b, (int)old, HI);
}

__device__ __forceinline__ void gload_lds16(const void* g, void* l) {
  __builtin_amdgcn_global_load_lds(
      (const __attribute__((address_space(1))) void*)g,
      (__attribute__((address_space(3))) void*)l, 16, 0, 0);
}

// ---- kernel 1: L2-normalize m rows -> fp8 e4m3, FRAGMENT-MAJOR layout ----
__global__ __launch_bounds__(256) void knorm_m(const float* __restrict__ m,
                                               u64* __restrict__ mnf) {
  const int wave = threadIdx.x >> 6, lane = threadIdx.x & 63;
  const int row = blockIdx.x * 4 + wave;
  const float* p = m + (size_t)row * N_F + lane * 8;
  float4 a = ((const float4*)p)[0];
  float4 b = ((const float4*)p)[1];
  float ss = a.x*a.x + a.y*a.y + a.z*a.z + a.w*a.w
           + b.x*b.x + b.y*b.y + b.z*b.z + b.w*b.w;
#pragma unroll
  for (int off = 1; off < 64; off <<= 1) ss += __shfl_xor(ss, off);
  const float inv = 1.0f / fmaxf(sqrtf(ss), 1e-12f);
  unsigned lo = pk8<false>(a.x*inv, a.y*inv, 0u);
  lo = pk8<true>(a.z*inv, a.w*inv, lo);
  unsigned hi = pk8<false>(b.x*inv, b.y*inv, 0u);
  hi = pk8<true>(b.z*inv, b.w*inv, hi);
  const u64 v = ((u64)hi << 32) | (u64)lo;
  const int i = lane >> 2, g = lane & 3;
  const int t = row >> 5, rb = (row >> 4) & 1, r16 = row & 15;
  mnf[((size_t)(t * 2 + rb) * 16 + i) * 64 + (r16 | (g << 4))] = v;
}

// ---- kernel 2: ABLATION TEMPLATE ----
// V=0 full (R9 clone)   V=1 no exp tail   V=2 no LDS reads
// V=3 no stage/vmcnt    V=4 no stage/vmcnt/barrier
template <int V>
__global__ __launch_bounds__(256, 4) void kmain(const float* __restrict__ x,
                                                const u64* __restrict__ mnf,
                                                float* __restrict__ acc_out) {
  __shared__ __align__(16) char mbuf[2][16384];
  const int tid = threadIdx.x, wave = tid >> 6, lane = tid & 63;
  const int r16 = lane & 15, g = lane >> 4;

  auto stage = [&](int t, int b) {
    const char* gp = (const char*)mnf + (size_t)t * 16384 + wave * 1024 + lane * 16;
    char* lp = &mbuf[b][wave * 1024];
#pragma unroll
    for (int q = 0; q < 4; ++q)
      gload_lds16(gp + q * 4096, lp + q * 4096);
  };

  stage(0, 0);
  stage(1, 1);

  long xb[16];
  const int row0 = blockIdx.x * 64 + wave * 16;
  const float* px = x + (size_t)(row0 + r16) * N_F + g * 8;
  float ss = 0.f;
#pragma unroll
  for (int i = 0; i < 16; ++i) {
    float4 a = *(const float4*)(px + i * 32);
    float4 b = *(const float4*)(px + i * 32 + 4);
    ss += a.x*a.x + a.y*a.y + a.z*a.z + a.w*a.w
        + b.x*b.x + b.y*b.y + b.z*b.z + b.w*b.w;
    unsigned lo = pk8<false>(a.x, a.y, 0u);
    lo = pk8<true>(a.z, a.w, lo);
    unsigned hi = pk8<false>(b.x, b.y, 0u);
    hi = pk8<true>(b.z, b.w, hi);
    xb[i] = (long)(((u64)hi << 32) | lo);
  }
  ss += __shfl_xor(ss, 16); ss += __shfl_xor(ss, 32);
  const float inv = 1.0f / fmaxf(sqrtf(ss), 1e-12f);

  float L = 0.f, S = 0.f;

  asm volatile("s_waitcnt vmcnt(4)" ::: "memory");
  __builtin_amdgcn_s_barrier();

#pragma unroll 1
  for (int t = 0; t < 32; ++t) {
    const int b = t & 1;
    if (V < 3) { if (t + 1 < 32) stage(t + 1, b ^ 1); }

    const char* mb = &mbuf[b][lane * 8];
    f32x4 a0e = {0.f,0.f,0.f,0.f}, a0o = {0.f,0.f,0.f,0.f};
    f32x4 a1e = {0.f,0.f,0.f,0.f}, a1o = {0.f,0.f,0.f,0.f};

    if (V != 2) {
      long f[16];
#pragma unroll
      for (int i = 0; i < 16; ++i) f[i] = *(const long*)(mb + i * 512);
      __builtin_amdgcn_s_setprio(1);
#pragma unroll
      for (int i = 0; i < 8; ++i) {
        a0e = __builtin_amdgcn_mfma_f32_16x16x32_fp8_fp8(f[2*i],   xb[2*i],   a0e, 0, 0, 0);
        a0o = __builtin_amdgcn_mfma_f32_16x16x32_fp8_fp8(f[2*i+1], xb[2*i+1], a0o, 0, 0, 0);
      }
      __builtin_amdgcn_s_setprio(0);
      long h[16];
#pragma unroll
      for (int i = 0; i < 16; ++i) h[i] = *(const long*)(mb + 8192 + i * 512);
      __builtin_amdgcn_s_setprio(1);
#pragma unroll
      for (int i = 0; i < 8; ++i) {
        a1e = __builtin_amdgcn_mfma_f32_16x16x32_fp8_fp8(h[2*i],   xb[2*i],   a1e, 0, 0, 0);
        a1o = __builtin_amdgcn_mfma_f32_16x16x32_fp8_fp8(h[2*i+1], xb[2*i+1], a1o, 0, 0, 0);
      }
      __builtin_amdgcn_s_setprio(0);
    } else {
      // no-LDS-read variant: MFMA on register operands only (same count)
      __builtin_amdgcn_s_setprio(1);
#pragma unroll
      for (int i = 0; i < 8; ++i) {
        a0e = __builtin_amdgcn_mfma_f32_16x16x32_fp8_fp8(xb[2*i],   xb[2*i],   a0e, 0, 0, 0);
        a0o = __builtin_amdgcn_mfma_f32_16x16x32_fp8_fp8(xb[2*i+1], xb[2*i+1], a0o, 0, 0, 0);
        a1e = __builtin_amdgcn_mfma_f32_16x16x32_fp8_fp8(xb[2*i],   xb[2*i+1], a1e, 0, 0, 0);
        a1o = __builtin_amdgcn_mfma_f32_16x16x32_fp8_fp8(xb[2*i+1], xb[2*i],   a1o, 0, 0, 0);
      }
      __builtin_amdgcn_s_setprio(0);
    }

    if (V != 1) {
#pragma unroll
      for (int r = 0; r < 4; ++r) {
        float y0 = (a0e[r] + a0o[r]) * inv;
        float e0 = __expf(y0); L += e0; S = fmaf(e0, y0, S);
        float y1 = (a1e[r] + a1o[r]) * inv;
        float e1 = __expf(y1); L += e1; S = fmaf(e1, y1, S);
      }
    } else {
      // keep MFMA results live without the exp tail
      L += (a0e[0] + a0o[0]) + (a1e[0] + a1o[0]);
      L += (a0e[1] + a0o[1]) + (a1e[1] + a1o[1]);
      L += (a0e[2] + a0o[2]) + (a1e[2] + a1o[2]);
      L += (a0e[3] + a0o[3]) + (a1e[3] + a1o[3]);
    }

    if (V < 3) { asm volatile("s_waitcnt vmcnt(0)" ::: "memory"); }
    if (V < 4) { __builtin_amdgcn_s_barrier(); }
  }

  L += __shfl_xor(L, 16); L += __shfl_xor(L, 32);
  S += __shfl_xor(S, 16); S += __shfl_xor(S, 32);
  float hh = 0.25f * (__logf(L) - S / L);
#pragma unroll
  for (int off = 1; off < 64; off <<= 1) hh += __shfl_xor(hh, off);
  if (lane == 0) atomicAdd(acc_out, hh);
}

// ---- kernel 3: finalize ----
__global__ void kfin(const float* __restrict__ acc, float* __restrict__ out) {
  const float mean = acc[0] * (1.0f / (float)N_ROWS);
  out[0] = mean;   // total
  out[1] = mean;   // intra
  out[2] = 0.0f;   // inter
}

extern "C" void kernel_launch(void* const* d_in, const int* in_sizes, int n_in,
                              void* d_out, int out_size, void* d_ws, size_t ws_size,
                              hipStream_t stream) {
  const float* x = (const float*)d_in[0];
  const float* m = (const float*)d_in[1];
  float* acc = (float*)d_ws;          // acc[0] = real, acc[1] = ablation scratch
  u64* mnf = (u64*)((char*)d_ws + 64);

  (void)hipMemsetAsync(d_ws, 0, 64, stream);
  knorm_m<<<256, 256, 0, stream>>>(m, mnf);
  kmain<0><<<1024, 256, 0, stream>>>(x, mnf, acc);       // real result
  kmain<1><<<1024, 256, 0, stream>>>(x, mnf, acc + 1);   // no exp tail
  kmain<2><<<1024, 256, 0, stream>>>(x, mnf, acc + 1);   // no LDS reads
  kmain<3><<<1024, 256, 0, stream>>>(x, mnf, acc + 1);   // no stage/vmcnt
  kmain<4><<<1024, 256, 0, stream>>>(x, mnf, acc + 1);   // + no barrier
  kfin<<<1, 1, 0, stream>>>(acc, (float*)d_out);
}

// Round 11
// 120.640 us; speedup vs baseline: 3.7410x; 3.7410x over previous
//
#include <hip/hip_runtime.h>
#include <hip/hip_bf16.h>

typedef float  f32x4  __attribute__((ext_vector_type(4)));
typedef unsigned long long u64;

#define N_ROWS 65536
#define N_F    512
#define N_CLU  1024

template <bool HI>
static __device__ __forceinline__ unsigned pk8(float a, float b, unsigned old) {
  return (unsigned)__builtin_amdgcn_cvt_pk_fp8_f32(a, b, (int)old, HI);
}

__device__ __forceinline__ void gload_lds16(const void* g, void* l) {
  __builtin_amdgcn_global_load_lds(
      (const __attribute__((address_space(1))) void*)g,
      (__attribute__((address_space(3))) void*)l, 16, 0, 0);
}

// ---- kernel 1: L2-normalize m rows -> fp8 e4m3, FRAGMENT-MAJOR layout ----
// mnf u64 index = ((t*2 + rb)*16 + i)*64 + (r16 | g<<4)
//   => tile t occupies bytes [t*16384, +16384) linearly; frag j (= rb*16+i)
//      of tile t is the 512B span at t*16384 + j*512, lane-consecutive.
__global__ __launch_bounds__(256) void knorm_m(const float* __restrict__ m,
                                               u64* __restrict__ mnf) {
  const int wave = threadIdx.x >> 6, lane = threadIdx.x & 63;
  const int row = blockIdx.x * 4 + wave;
  const float* p = m + (size_t)row * N_F + lane * 8;
  float4 a = ((const float4*)p)[0];
  float4 b = ((const float4*)p)[1];
  float ss = a.x*a.x + a.y*a.y + a.z*a.z + a.w*a.w
           + b.x*b.x + b.y*b.y + b.z*b.z + b.w*b.w;
#pragma unroll
  for (int off = 1; off < 64; off <<= 1) ss += __shfl_xor(ss, off);
  const float inv = 1.0f / fmaxf(sqrtf(ss), 1e-12f);
  unsigned lo = pk8<false>(a.x*inv, a.y*inv, 0u);
  lo = pk8<true>(a.z*inv, a.w*inv, lo);
  unsigned hi = pk8<false>(b.x*inv, b.y*inv, 0u);
  hi = pk8<true>(b.z*inv, b.w*inv, hi);
  const u64 v = ((u64)hi << 32) | (u64)lo;
  const int i = lane >> 2, g = lane & 3;
  const int t = row >> 5, rb = (row >> 4) & 1, r16 = row & 15;
  mnf[((size_t)(t * 2 + rb) * 16 + i) * 64 + (r16 | (g << 4))] = v;
}

// ---- kernel 2: fused x @ mn^T (fp8 MFMA) -> entropy partials ----
// T4 structure: 3-buffer LDS ring, ONE barrier per tile, counted vmcnt(4)
// (never drain to 0) -> staging loads stay in flight across two barriers.
// iter t: wait vmcnt(4) [stage(t) landed, stage(t+1) in flight] -> barrier
//         -> issue stage(t+2) [overwrites buf read at t-1: WAR-safe]
//         -> batched ds_reads + MFMA clusters (setprio) + exp tail.
__global__ __launch_bounds__(256, 3) void kmain(const float* __restrict__ x,
                                                const u64* __restrict__ mnf,
                                                float* __restrict__ acc_out) {
  __shared__ __align__(16) char mbuf[3][16384];   // 48 KiB ring
  const int tid = threadIdx.x, wave = tid >> 6, lane = tid & 63;
  const int r16 = lane & 15, g = lane >> 4;

  auto stage = [&](int t, int b) {
    const char* gp = (const char*)mnf + (size_t)t * 16384 + wave * 1024 + lane * 16;
    char* lp = &mbuf[b][wave * 1024];   // wave-uniform base; HW adds lane*16
#pragma unroll
    for (int q = 0; q < 4; ++q)
      gload_lds16(gp + q * 4096, lp + q * 4096);
  };

  stage(0, 0);    // these retire during the x prologue
  stage(1, 1);

  // ---- x prologue, single pass: pack RAW fp8 + accumulate sum-of-squares ----
  long xb[16];
  const int row0 = blockIdx.x * 64 + wave * 16;
  const float* px = x + (size_t)(row0 + r16) * N_F + g * 8;
  float ss = 0.f;
#pragma unroll
  for (int i = 0; i < 16; ++i) {
    float4 a = *(const float4*)(px + i * 32);
    float4 b = *(const float4*)(px + i * 32 + 4);
    ss += a.x*a.x + a.y*a.y + a.z*a.z + a.w*a.w
        + b.x*b.x + b.y*b.y + b.z*b.z + b.w*b.w;
    unsigned lo = pk8<false>(a.x, a.y, 0u);
    lo = pk8<true>(a.z, a.w, lo);
    unsigned hi = pk8<false>(b.x, b.y, 0u);
    hi = pk8<true>(b.z, b.w, hi);
    xb[i] = (long)(((u64)hi << 32) | lo);
  }
  ss += __shfl_xor(ss, 16); ss += __shfl_xor(ss, 32);
  const float inv = 1.0f / fmaxf(sqrtf(ss), 1e-12f);   // per-lane = x-row r16

  float L = 0.f, S = 0.f;
  int bc = 0, bs = 2;   // compute-buffer, stage-buffer ring indices

#pragma unroll 1
  for (int t = 0; t < 32; ++t) {
    // stage(t) complete (stage(t+1)'s 4 loads may remain in flight)
    asm volatile("s_waitcnt vmcnt(4)" ::: "memory");
    __builtin_amdgcn_s_barrier();
    // all waves finished reading buf[bs] (= buffer of tile t-1) -> overwrite
    if (t + 2 < 32) stage(t + 2, bs);

    const char* mb = &mbuf[bc][lane * 8];
    f32x4 a0e = {0.f,0.f,0.f,0.f}, a0o = {0.f,0.f,0.f,0.f};
    f32x4 a1e = {0.f,0.f,0.f,0.f}, a1o = {0.f,0.f,0.f,0.f};

    // ---- half 0 (clusters 0-15): batch reads, then MFMA cluster ----
    long f[16];
#pragma unroll
    for (int i = 0; i < 16; ++i) f[i] = *(const long*)(mb + i * 512);
    __builtin_amdgcn_s_setprio(1);
#pragma unroll
    for (int i = 0; i < 8; ++i) {
      a0e = __builtin_amdgcn_mfma_f32_16x16x32_fp8_fp8(f[2*i],   xb[2*i],   a0e, 0, 0, 0);
      a0o = __builtin_amdgcn_mfma_f32_16x16x32_fp8_fp8(f[2*i+1], xb[2*i+1], a0o, 0, 0, 0);
    }
    __builtin_amdgcn_s_setprio(0);

    // ---- half 1 (clusters 16-31) ----
    long h[16];
#pragma unroll
    for (int i = 0; i < 16; ++i) h[i] = *(const long*)(mb + 8192 + i * 512);
    __builtin_amdgcn_s_setprio(1);
#pragma unroll
    for (int i = 0; i < 8; ++i) {
      a1e = __builtin_amdgcn_mfma_f32_16x16x32_fp8_fp8(h[2*i],   xb[2*i],   a1e, 0, 0, 0);
      a1o = __builtin_amdgcn_mfma_f32_16x16x32_fp8_fp8(h[2*i+1], xb[2*i+1], a1o, 0, 0, 0);
    }
    __builtin_amdgcn_s_setprio(0);

    // ---- entropy partials ----
#pragma unroll
    for (int r = 0; r < 4; ++r) {
      float y0 = (a0e[r] + a0o[r]) * inv;
      float e0 = __expf(y0); L += e0; S = fmaf(e0, y0, S);
      float y1 = (a1e[r] + a1o[r]) * inv;
      float e1 = __expf(y1); L += e1; S = fmaf(e1, y1, S);
    }

    bc = (bc == 2) ? 0 : bc + 1;
    bs = (bs == 2) ? 0 : bs + 1;
  }

  // ---- finish: reduce the 4 g-groups (disjoint cluster subsets per row) ----
  L += __shfl_xor(L, 16); L += __shfl_xor(L, 32);
  S += __shfl_xor(S, 16); S += __shfl_xor(S, 32);
  // each row's (L,S) now replicated on 4 lanes -> weight 1/4, butterfly-sum
  float hh = 0.25f * (__logf(L) - S / L);
#pragma unroll
  for (int off = 1; off < 64; off <<= 1) hh += __shfl_xor(hh, off);
  if (lane == 0) atomicAdd(acc_out, hh);
}

// ---- kernel 3: finalize ----
__global__ void kfin(const float* __restrict__ acc, float* __restrict__ out) {
  const float mean = acc[0] * (1.0f / (float)N_ROWS);
  out[0] = mean;   // total
  out[1] = mean;   // intra
  out[2] = 0.0f;   // inter
}

extern "C" void kernel_launch(void* const* d_in, const int* in_sizes, int n_in,
                              void* d_out, int out_size, void* d_ws, size_t ws_size,
                              hipStream_t stream) {
  const float* x = (const float*)d_in[0];
  const float* m = (const float*)d_in[1];
  float* acc = (float*)d_ws;
  u64* mnf = (u64*)((char*)d_ws + 64);

  (void)hipMemsetAsync(d_ws, 0, 64, stream);
  knorm_m<<<256, 256, 0, stream>>>(m, mnf);
  kmain<<<1024, 256, 0, stream>>>(x, mnf, acc);
  kfin<<<1, 1, 0, stream>>>(acc, (float*)d_out);
}